// Round 1
// baseline (215.704 us; speedup 1.0000x reference)
//
#include <hip/hip_runtime.h>

// 4-level Haar DWT, one kernel per level.
// Each thread: reads a 2x4 input patch (two float4 rows), emits 2 output
// pixels for each of the 4 subbands (float2 stores).
// dst plane layout: (b*12 + 4*c + s) * (h*w), s in {LL,LH,HL,HH}.
// dup=1: channel nC-1 results are also written to channel-group nC
// (reference bug: b4 = g4 at level 4).
__global__ __launch_bounds__(256) void dwt_level_kernel(
    const float* __restrict__ src, float* __restrict__ dst,
    int W,            // input plane width (input height = 2*h)
    int h, int shift, // output h; shift = log2(w/2) (threads per output row)
    long src_b_stride, long src_c_stride,   // element strides of src planes
    int nC, int dup)
{
    int pid = blockIdx.x * blockDim.x + threadIdx.x;
    int npix = h << shift;          // threads per plane
    if (pid >= npix) return;

    int plane = blockIdx.y;
    int b = plane / nC;
    int c = plane - b * nC;

    int jw = pid & ((1 << shift) - 1);   // output column pair index
    int i  = pid >> shift;               // output row

    const float* sp = src + (long)b * src_b_stride + (long)c * src_c_stride;
    const float4 r0 = *((const float4*)(sp + (long)(2 * i)     * W) + jw);
    const float4 r1 = *((const float4*)(sp + (long)(2 * i + 1) * W) + jw);

    // pixel 0: a=r0.x b=r0.y c=r1.x d=r1.y ; pixel 1: a=r0.z b=r0.w c=r1.z d=r1.w
    float L00 = (r0.x + r1.x) * 0.5f;  // haar_y L at col 2j
    float L01 = (r0.y + r1.y) * 0.5f;  // col 2j+1
    float H00 = fabsf(r0.x - r1.x);
    float H01 = fabsf(r0.y - r1.y);
    float L10 = (r0.z + r1.z) * 0.5f;
    float L11 = (r0.w + r1.w) * 0.5f;
    float H10 = fabsf(r0.z - r1.z);
    float H11 = fabsf(r0.w - r1.w);

    float2 ll = make_float2((L00 + L01) * 0.5f, (L10 + L11) * 0.5f);
    float2 lh = make_float2(fabsf(L00 - L01), fabsf(L10 - L11));
    float2 hl = make_float2((H00 + H01) * 0.5f, (H10 + H11) * 0.5f);
    float2 hh = make_float2(fabsf(H00 - H01), fabsf(H10 - H11));

    int w = 2 << shift;                 // output width
    long hw = (long)h * w;
    float* dp = dst + (long)(b * 12 + 4 * c) * hw + (long)i * w + 2 * jw;

    *(float2*)(dp + 0 * hw) = ll;
    *(float2*)(dp + 1 * hw) = lh;
    *(float2*)(dp + 2 * hw) = hl;
    *(float2*)(dp + 3 * hw) = hh;

    if (dup && c == nC - 1) {
        float* dp2 = dp + 4 * hw;
        *(float2*)(dp2 + 0 * hw) = ll;
        *(float2*)(dp2 + 1 * hw) = lh;
        *(float2*)(dp2 + 2 * hw) = hl;
        *(float2*)(dp2 + 3 * hw) = hh;
    }
}

extern "C" void kernel_launch(void* const* d_in, const int* in_sizes, int n_in,
                              void* d_out, int out_size, void* d_ws, size_t ws_size,
                              hipStream_t stream) {
    const float* x = (const float*)d_in[0];
    float* out = (float*)d_out;

    const long t1_off = 0;
    const long t2_off = t1_off + 32L * 12 * 256 * 256;
    const long t3_off = t2_off + 32L * 12 * 128 * 128;
    const long t4_off = t3_off + 32L * 12 * 64 * 64;

    dim3 blk(256);
    // Level 1: src x (32,3,512,512) -> t1 (32,12,256,256)
    dwt_level_kernel<<<dim3(128, 96), blk, 0, stream>>>(
        x, out + t1_off, 512, 256, 7, 3L * 512 * 512, 512L * 512, 3, 0);
    // Level 2: src t1 LL planes (stride 12 planes/b, 4 planes/c) -> t2
    dwt_level_kernel<<<dim3(32, 96), blk, 0, stream>>>(
        out + t1_off, out + t2_off, 256, 128, 6, 12L * 256 * 256, 4L * 256 * 256, 3, 0);
    // Level 3
    dwt_level_kernel<<<dim3(8, 96), blk, 0, stream>>>(
        out + t2_off, out + t3_off, 128, 64, 5, 12L * 128 * 128, 4L * 128 * 128, 3, 0);
    // Level 4: only r,g computed; g duplicated into the blue slot (b4 = g4)
    dwt_level_kernel<<<dim3(2, 64), blk, 0, stream>>>(
        out + t3_off, out + t4_off, 64, 32, 4, 12L * 64 * 64, 4L * 64 * 64, 2, 1);
}